// Round 3
// baseline (198.884 us; speedup 1.0000x reference)
//
#include <hip/hip_runtime.h>
#include <stdint.h>

// ---------------------------------------------------------------------------
// BinaryLinear: out[M,N] = x[M,K] @ sign(W[N,K])^T + bias[N]
// M=8192, K=2048, N=2048, fp32 in/out.
// Round 7: faithful port of the m201-verified 256x256 8-phase configuration.
//   - 16x16x32 MFMA (the measured-conflict-free config), 512 thr, 8 waves
//     (2M x 4N), per-wave 128x64 output = acc f32x4[8][4].
//   - LDS: 2 buffers x (A 256x64 + B 256x64) bf16 = 128 KB, each operand as
//     two 128-row half-tiles. st_16x32 swizzle: local byte ^= ((byte>>9)&1)<<5
//     == 16B-chunk-bit1 ^= row-bit2. Involution, applied on the global source
//     during global_load_lds staging (LDS dest linear) and on the ds_read
//     addresses (rule #21 both-sides discipline).
//   - Schedule per K-tile T: 4 M-quadrant phases. Phase 0: stage ALL 4
//     half-tiles of T+1 into the other buffer (8 gload_lds) + read B frags
//     (8 b128, register-resident for the tile) + 4 A reads; phases 1-3: 4 A
//     reads each. Each phase: reads -> bar -> lgkm(0) -> setprio(1) -> 16
//     MFMA -> setprio(0); phase 3 appends per-wave vmcnt(0) (certifies own
//     stages; ~free: 3-phase lag > HBM latency) before the trailing bar.
//     vmcnt never waits on recently-issued loads (T4 property preserved).
//   - Epilogue: direct scalar stores, C/D map col=lane&15,
//     row=(lane>>4)*4+reg (m89/m91 HW-verified).
// Prep kernels (cvt_x, bin_w) unchanged (harness-verified R4).
// ---------------------------------------------------------------------------

typedef __bf16 bf16x8 __attribute__((ext_vector_type(8)));
typedef float f32x4 __attribute__((ext_vector_type(4)));

typedef const __attribute__((address_space(1))) void* gas_ptr;
typedef __attribute__((address_space(3))) void* lds_ptr;

__device__ __forceinline__ unsigned short f2bf_rne(float f) {
    unsigned int u = __builtin_bit_cast(unsigned int, f);
    u += 0x7fffu + ((u >> 16) & 1u);   // round-to-nearest-even
    return (unsigned short)(u >> 16);
}

__global__ __launch_bounds__(256) void cvt_x_kernel(const float* __restrict__ in,
                                                    unsigned short* __restrict__ out,
                                                    int n8) {
    int i = blockIdx.x * 256 + threadIdx.x;
    if (i >= n8) return;
    const float4* p = reinterpret_cast<const float4*>(in + (size_t)i * 8);
    float4 f0 = p[0], f1 = p[1];
    union { unsigned short s[8]; uint4 v; } o;
    o.s[0] = f2bf_rne(f0.x); o.s[1] = f2bf_rne(f0.y);
    o.s[2] = f2bf_rne(f0.z); o.s[3] = f2bf_rne(f0.w);
    o.s[4] = f2bf_rne(f1.x); o.s[5] = f2bf_rne(f1.y);
    o.s[6] = f2bf_rne(f1.z); o.s[7] = f2bf_rne(f1.w);
    *reinterpret_cast<uint4*>(out + (size_t)i * 8) = o.v;
}

__global__ __launch_bounds__(256) void bin_w_kernel(const float* __restrict__ in,
                                                    unsigned short* __restrict__ out,
                                                    int n4) {
    int i = blockIdx.x * 256 + threadIdx.x;
    if (i >= n4) return;
    float4 f = reinterpret_cast<const float4*>(in)[i];
    union { unsigned short s[4]; uint2 v; } o;
    o.s[0] = (f.x >= 0.f) ? 0x3F80u : 0xBF80u;
    o.s[1] = (f.y >= 0.f) ? 0x3F80u : 0xBF80u;
    o.s[2] = (f.z >= 0.f) ? 0x3F80u : 0xBF80u;
    o.s[3] = (f.w >= 0.f) ? 0x3F80u : 0xBF80u;
    reinterpret_cast<uint2*>(out)[i] = o.v;
}

#define WAITVM(N) asm volatile("s_waitcnt vmcnt(" #N ")" ::: "memory")

__device__ __forceinline__ void block_bar() {
    asm volatile("" ::: "memory");
    __builtin_amdgcn_s_barrier();
    asm volatile("" ::: "memory");
}

// LDS map per buffer (ushort offsets): A-h0 @0, A-h1 @8192, B-h0 @16384,
// B-h1 @24576. Half-tile = 128 rows x 64 bf16 (128B rows, 8 x 16B chunks).
// Swizzle (within half-tile): phys_chunk = chunk ^ ((row>>2 & 1) << 1).
__global__ __launch_bounds__(512, 2) void gemm_bin_kernel(
    const unsigned short* __restrict__ A,   // bf16 bits [M][K]
    const unsigned short* __restrict__ B,   // bf16 bits [N][K]
    const float* __restrict__ bias,         // [N]
    float* __restrict__ C,                  // [M][N]
    int M, int N, int K)
{
    __shared__ __align__(16) unsigned char smem_raw[131072];
    unsigned short* const sm = (unsigned short*)smem_raw;

    const int tid  = threadIdx.x;
    const int lane = tid & 63;
    const int wave = tid >> 6;    // 0..7
    const int wm   = wave >> 2;   // 0..1  (M half: 128 rows)
    const int wn   = wave & 3;    // 0..3  (N quarter: 64 cols)
    const int bm   = blockIdx.y;  // 32
    const int bn   = blockIdx.x;  // 8

    const unsigned short* __restrict__ Agb = A + (size_t)(bm * 256) * K;
    const unsigned short* __restrict__ Bgb = B + (size_t)(bn * 256) * K;

    const int r15 = lane & 15;    // frag row (A) / col (B)
    const int kc  = lane >> 4;    // k-chunk 0..3 within K=32 slice
    const int sw  = ((r15 >> 2) & 1) << 1;   // st_16x32 XOR (row-bit2 -> chunk-bit1)

    // Frag read bases (ushort, buffer-relative); mf/nf folded as immediates.
    // A(mf,kk): wm*8192 + mf*1024 + r15*64 + ((kk*4+kc)^sw)*8
    const int baseA0 = wm * 8192 + r15 * 64 + ((kc    ) ^ sw) * 8;
    const int baseA1 = wm * 8192 + r15 * 64 + ((kc + 4) ^ sw) * 8;
    // B(nf,kk): 16384 + (wn>>1)*8192 + (wn&1)*4096 + nf*1024 + r15*64 + ...
    const int bBq    = 16384 + (wn >> 1) * 8192 + (wn & 1) * 4096 + r15 * 64;
    const int baseB0 = bBq + ((kc    ) ^ sw) * 8;
    const int baseB1 = bBq + ((kc + 4) ^ sw) * 8;

    // Staging geometry: half-tile = 1024 chunks; thread stages g = j*512+tid.
    // LDS dest linear (g*16B); global source column pre-swizzled (involution).
    int gsoff[2], ldoff[2];
#pragma unroll
    for (int j = 0; j < 2; ++j) {
        const int g  = j * 512 + tid;
        const int rl = g >> 3;
        const int c  = (g & 7) ^ (((rl >> 2) & 1) << 1);
        gsoff[j] = rl * K + c * 8;   // elements within (half-tile) panel
        ldoff[j] = g * 8;            // ushorts within region
    }

    // Bias preload (kept live so it doesn't reload mid-pipeline).
    const int colb = bn * 256 + wn * 64;
    float bv[4];
#pragma unroll
    for (int nf = 0; nf < 4; ++nf) {
        bv[nf] = bias[colb + nf * 16 + r15];
        asm volatile("" :: "v"(bv[nf]));
    }

    f32x4 acc[8][4];
#pragma unroll
    for (int m = 0; m < 8; ++m)
#pragma unroll
        for (int n = 0; n < 4; ++n)
#pragma unroll
            for (int r = 0; r < 4; ++r) acc[m][n][r] = 0.f;

    bf16x8 bfr[4][2];   // B frags, register-resident per K-tile

    auto stageAll = [&](int T1, unsigned short* dst) {
        const unsigned short* ga = Agb + (size_t)T1 * 64;
        const unsigned short* gb = Bgb + (size_t)T1 * 64;
#pragma unroll
        for (int j = 0; j < 2; ++j)
            __builtin_amdgcn_global_load_lds((gas_ptr)(ga + gsoff[j]),
                                             (lds_ptr)(dst + ldoff[j]), 16, 0, 0);
#pragma unroll
        for (int j = 0; j < 2; ++j)
            __builtin_amdgcn_global_load_lds((gas_ptr)(ga + (size_t)128 * K + gsoff[j]),
                                             (lds_ptr)(dst + 8192 + ldoff[j]), 16, 0, 0);
#pragma unroll
        for (int j = 0; j < 2; ++j)
            __builtin_amdgcn_global_load_lds((gas_ptr)(gb + gsoff[j]),
                                             (lds_ptr)(dst + 16384 + ldoff[j]), 16, 0, 0);
#pragma unroll
        for (int j = 0; j < 2; ++j)
            __builtin_amdgcn_global_load_lds((gas_ptr)(gb + (size_t)128 * K + gsoff[j]),
                                             (lds_ptr)(dst + 24576 + ldoff[j]), 16, 0, 0);
    };

    const int KT = K >> 6;   // 32 K-tiles of 64

    // Prologue: stage tile 0 into buf0; certify; sync.
    stageAll(0, sm);
    WAITVM(0);
    block_bar();

    for (int T = 0; T < KT; ++T) {
        const unsigned short* bb = sm + (T & 1) * 32768;
        unsigned short* nb = sm + ((T + 1) & 1) * 32768;
#pragma unroll
        for (int mh = 0; mh < 4; ++mh) {
            if (mh == 0) {
                if (T + 1 < KT) stageAll(T + 1, nb);   // other buffer: race-free
#pragma unroll
                for (int nf = 0; nf < 4; ++nf) {
                    bfr[nf][0] = *reinterpret_cast<const bf16x8*>(bb + baseB0 + nf * 1024);
                    bfr[nf][1] = *reinterpret_cast<const bf16x8*>(bb + baseB1 + nf * 1024);
                }
            }
            bf16x8 af[2][2];
#pragma unroll
            for (int mi = 0; mi < 2; ++mi) {
                af[mi][0] = *reinterpret_cast<const bf16x8*>(bb + baseA0 + (mh * 2 + mi) * 1024);
                af[mi][1] = *reinterpret_cast<const bf16x8*>(bb + baseA1 + (mh * 2 + mi) * 1024);
            }
            block_bar();
            asm volatile("s_waitcnt lgkmcnt(0)" ::: "memory");
            __builtin_amdgcn_sched_barrier(0);
            __builtin_amdgcn_s_setprio(1);
#pragma unroll
            for (int kk = 0; kk < 2; ++kk)
#pragma unroll
                for (int mi = 0; mi < 2; ++mi)
#pragma unroll
                    for (int nf = 0; nf < 4; ++nf)
                        acc[mh * 2 + mi][nf] = __builtin_amdgcn_mfma_f32_16x16x32_bf16(
                            af[mi][kk], bfr[nf][kk], acc[mh * 2 + mi][nf], 0, 0, 0);
            __builtin_amdgcn_sched_barrier(0);
            __builtin_amdgcn_s_setprio(0);
            if (mh == 3) { WAITVM(0); }   // own stages: ~3-phase lag, near-free
            block_bar();
        }
    }

    // Epilogue: direct stores. 16x16 C/D: col = lane&15, row = (lane>>4)*4+reg.
    const int row0 = bm * 256 + wm * 128 + kc * 4;
#pragma unroll
    for (int mf = 0; mf < 8; ++mf)
#pragma unroll
        for (int nf = 0; nf < 4; ++nf) {
            float* cp = C + (size_t)(row0 + mf * 16) * N + colb + nf * 16 + r15;
#pragma unroll
            for (int r = 0; r < 4; ++r)
                cp[(size_t)r * N] = acc[mf][nf][r] + bv[nf];
        }
}

extern "C" void kernel_launch(void* const* d_in, const int* in_sizes, int n_in,
                              void* d_out, int out_size, void* d_ws, size_t ws_size,
                              hipStream_t stream) {
    const float* x    = (const float*)d_in[0];   // [M, K]
    const float* w    = (const float*)d_in[1];   // [N, K]
    const float* bias = (const float*)d_in[2];   // [N]
    float* out = (float*)d_out;

    const int K = 2048;                 // IN
    const int N = in_sizes[2];          // OUT = 2048
    const int M = in_sizes[0] / K;      // 8192

    unsigned short* xb = (unsigned short*)d_ws;   // [M,K] bf16: 32 MB
    unsigned short* wb = xb + (size_t)M * K;      // [N,K] bf16 +-1: 8 MB

    const int nx8 = (M * K) / 8;
    const int nw4 = (N * K) / 4;
    cvt_x_kernel<<<(nx8 + 255) / 256, 256, 0, stream>>>(x, xb, nx8);
    bin_w_kernel<<<(nw4 + 255) / 256, 256, 0, stream>>>(w, wb, nw4);

    dim3 grid(N / 256, M / 256);        // (8, 32) = 256 blocks, 1/CU
    gemm_bin_kernel<<<grid, 512, 0, stream>>>(xb, wb, bias, out, M, N, K);
}

// Round 4
// 191.329 us; speedup vs baseline: 1.0395x; 1.0395x over previous
//
#include <hip/hip_runtime.h>
#include <stdint.h>

// ---------------------------------------------------------------------------
// BinaryLinear: out[M,N] = x[M,K] @ sign(W[N,K])^T + bias[N]
// M=8192, K=2048, N=2048, fp32 in/out.
// Round 8: R7 structure with the drain-0 poison removed.
//   Theory: asm "memory" clobbers around s_barrier/waitcnt force the waitcnt
//   pass to emit s_waitcnt vmcnt(0) (global_load_lds completion is vmcnt-
//   tracked), converting the counted-vmcnt schedule into drain-0-per-barrier
//   (the documented 839-912 TF plateau; R5/R6/R7 all landed there).
//   - All in-loop barriers: bare __builtin_amdgcn_s_barrier(), no clobbers.
//   - All s_waitcnt asm: clobber-free (template-faithful).
//   - Cross-tile publish ordering: sched_barrier(0) + one "memory" fence per
//     K-tile placed right after the vmcnt(0) guard, where outstanding
//     counters are provably 0 => forced drain is free.
//   - Staging spread: A half-tiles (4 loads) in phase 0, B half-tiles (4) in
//     phase 1 => phase-3 guard has >=2-phase lag (> HBM latency, no stall).
//   - No sched_barrier around MFMA (deps are register-tracked; pinning hurts).
//   - Layouts/swizzle/staging math byte-identical to R7 (harness-verified).
//   - Prep kernels merged into one launch (same math).
// ---------------------------------------------------------------------------

typedef __bf16 bf16x8 __attribute__((ext_vector_type(8)));
typedef float f32x4 __attribute__((ext_vector_type(4)));

typedef const __attribute__((address_space(1))) void* gas_ptr;
typedef __attribute__((address_space(3))) void* lds_ptr;

__device__ __forceinline__ unsigned short f2bf_rne(float f) {
    unsigned int u = __builtin_bit_cast(unsigned int, f);
    u += 0x7fffu + ((u >> 16) & 1u);   // round-to-nearest-even
    return (unsigned short)(u >> 16);
}

// Merged prep: blocks [0,nxB) convert x fp32->bf16 (8/thr); blocks [nxB,..)
// binarize W to bf16 +-1 (4/thr). Same math as the verified R4 kernels.
__global__ __launch_bounds__(256) void prep_kernel(
    const float* __restrict__ x, const float* __restrict__ w,
    unsigned short* __restrict__ xb, unsigned short* __restrict__ wb,
    int nx8, int nxB, int nw4)
{
    const int b = blockIdx.x;
    if (b < nxB) {
        int i = b * 256 + threadIdx.x;
        if (i >= nx8) return;
        const float4* p = reinterpret_cast<const float4*>(x + (size_t)i * 8);
        float4 f0 = p[0], f1 = p[1];
        union { unsigned short s[8]; uint4 v; } o;
        o.s[0] = f2bf_rne(f0.x); o.s[1] = f2bf_rne(f0.y);
        o.s[2] = f2bf_rne(f0.z); o.s[3] = f2bf_rne(f0.w);
        o.s[4] = f2bf_rne(f1.x); o.s[5] = f2bf_rne(f1.y);
        o.s[6] = f2bf_rne(f1.z); o.s[7] = f2bf_rne(f1.w);
        *reinterpret_cast<uint4*>(xb + (size_t)i * 8) = o.v;
    } else {
        int i = (b - nxB) * 256 + threadIdx.x;
        if (i >= nw4) return;
        float4 f = reinterpret_cast<const float4*>(w)[i];
        union { unsigned short s[4]; uint2 v; } o;
        o.s[0] = (f.x >= 0.f) ? 0x3F80u : 0xBF80u;
        o.s[1] = (f.y >= 0.f) ? 0x3F80u : 0xBF80u;
        o.s[2] = (f.z >= 0.f) ? 0x3F80u : 0xBF80u;
        o.s[3] = (f.w >= 0.f) ? 0x3F80u : 0xBF80u;
        reinterpret_cast<uint2*>(wb)[i] = o.v;
    }
}

// Clobber-free waits (template-faithful; no forced drains).
#define WAITLGKM0 asm volatile("s_waitcnt lgkmcnt(0)")
#define WAITLGKM8 asm volatile("s_waitcnt lgkmcnt(8)")
#define WAITVM0   asm volatile("s_waitcnt vmcnt(0)")
#define SBAR      __builtin_amdgcn_s_barrier()
#define SCHEDB    __builtin_amdgcn_sched_barrier(0)

// LDS map per buffer (ushort offsets): A-h0 @0, A-h1 @8192, B-h0 @16384,
// B-h1 @24576. Half-tile = 128 rows x 64 bf16 (128B rows, 8 x 16B chunks).
// Swizzle: phys_chunk = chunk ^ (((row>>2)&1)<<1), applied on the global
// source during staging (LDS dest linear) and on ds_read addresses.
__global__ __launch_bounds__(512, 2) void gemm_bin_kernel(
    const unsigned short* __restrict__ A,   // bf16 bits [M][K]
    const unsigned short* __restrict__ B,   // bf16 bits [N][K]
    const float* __restrict__ bias,         // [N]
    float* __restrict__ C,                  // [M][N]
    int M, int N, int K)
{
    __shared__ __align__(16) unsigned char smem_raw[131072];
    unsigned short* const sm = (unsigned short*)smem_raw;

    const int tid  = threadIdx.x;
    const int lane = tid & 63;
    const int wave = tid >> 6;    // 0..7
    const int wm   = wave >> 2;   // 0..1  (M half: 128 rows)
    const int wn   = wave & 3;    // 0..3  (N quarter: 64 cols)
    const int bm   = blockIdx.y;  // 32
    const int bn   = blockIdx.x;  // 8

    const unsigned short* __restrict__ Agb = A + (size_t)(bm * 256) * K;
    const unsigned short* __restrict__ Bgb = B + (size_t)(bn * 256) * K;

    const int r15 = lane & 15;    // frag row (A) / col (B)
    const int kc  = lane >> 4;    // k-chunk 0..3 within K=32 slice
    const int sw  = ((r15 >> 2) & 1) << 1;

    // Frag read bases (ushort, buffer-relative) — byte-identical to R7.
    const int baseA0 = wm * 8192 + r15 * 64 + ((kc    ) ^ sw) * 8;
    const int baseA1 = wm * 8192 + r15 * 64 + ((kc + 4) ^ sw) * 8;
    const int bBq    = 16384 + (wn >> 1) * 8192 + (wn & 1) * 4096 + r15 * 64;
    const int baseB0 = bBq + ((kc    ) ^ sw) * 8;
    const int baseB1 = bBq + ((kc + 4) ^ sw) * 8;

    // Staging geometry (byte-identical to R7).
    int gsoff[2], ldoff[2];
#pragma unroll
    for (int j = 0; j < 2; ++j) {
        const int g  = j * 512 + tid;
        const int rl = g >> 3;
        const int c  = (g & 7) ^ (((rl >> 2) & 1) << 1);
        gsoff[j] = rl * K + c * 8;
        ldoff[j] = g * 8;
    }

    const int colb = bn * 256 + wn * 64;
    float bv[4];
#pragma unroll
    for (int nf = 0; nf < 4; ++nf) {
        bv[nf] = bias[colb + nf * 16 + r15];
        asm volatile("" :: "v"(bv[nf]));
    }

    f32x4 acc[8][4];
#pragma unroll
    for (int m = 0; m < 8; ++m)
#pragma unroll
        for (int n = 0; n < 4; ++n)
#pragma unroll
            for (int r = 0; r < 4; ++r) acc[m][n][r] = 0.f;

    bf16x8 bfr[4][2];   // B frags, register-resident per K-tile

    auto stage2 = [&](const unsigned short* gsrc, unsigned short* dst) {
#pragma unroll
        for (int j = 0; j < 2; ++j)
            __builtin_amdgcn_global_load_lds((gas_ptr)(gsrc + gsoff[j]),
                                             (lds_ptr)(dst + ldoff[j]), 16, 0, 0);
    };

    const int KT = K >> 6;   // 32 K-tiles of 64

    // Prologue: stage tile 0 into buf0; free drain (nothing else in flight).
    stage2(Agb,                   sm);
    stage2(Agb + (size_t)128 * K, sm + 8192);
    stage2(Bgb,                   sm + 16384);
    stage2(Bgb + (size_t)128 * K, sm + 24576);
    WAITVM0;
    SBAR;
    SCHEDB;
    asm volatile("" ::: "memory");   // free: counters are 0 here

    for (int T = 0; T < KT; ++T) {
        const unsigned short* bb = sm + (T & 1) * 32768;
        unsigned short* nb = sm + ((T + 1) & 1) * 32768;
        const int pf = (T + 1 < KT);
        const unsigned short* gaN = Agb + (size_t)(T + 1) * 64;
        const unsigned short* gbN = Bgb + (size_t)(T + 1) * 64;

#pragma unroll
        for (int mh = 0; mh < 4; ++mh) {
            if (mh == 0) {
#pragma unroll
                for (int nf = 0; nf < 4; ++nf) {
                    bfr[nf][0] = *reinterpret_cast<const bf16x8*>(bb + baseB0 + nf * 1024);
                    bfr[nf][1] = *reinterpret_cast<const bf16x8*>(bb + baseB1 + nf * 1024);
                }
            }
            bf16x8 af[2][2];
#pragma unroll
            for (int mi = 0; mi < 2; ++mi) {
                af[mi][0] = *reinterpret_cast<const bf16x8*>(bb + baseA0 + (mh * 2 + mi) * 1024);
                af[mi][1] = *reinterpret_cast<const bf16x8*>(bb + baseA1 + (mh * 2 + mi) * 1024);
            }
            if (mh == 0 && pf) {                 // stage A halves of T+1
                stage2(gaN,                   nb);
                stage2(gaN + (size_t)128 * K, nb + 8192);
            }
            if (mh == 1 && pf) {                 // stage B halves of T+1
                stage2(gbN,                   nb + 16384);
                stage2(gbN + (size_t)128 * K, nb + 24576);
            }
            if (mh == 0) WAITLGKM8;
            SBAR;
            WAITLGKM0;
            __builtin_amdgcn_s_setprio(1);
#pragma unroll
            for (int kk = 0; kk < 2; ++kk)
#pragma unroll
                for (int mi = 0; mi < 2; ++mi)
#pragma unroll
                    for (int nf = 0; nf < 4; ++nf)
                        acc[mh * 2 + mi][nf] = __builtin_amdgcn_mfma_f32_16x16x32_bf16(
                            af[mi][kk], bfr[nf][kk], acc[mh * 2 + mi][nf], 0, 0, 0);
            __builtin_amdgcn_s_setprio(0);
            if (mh == 3) WAITVM0;   // >=2-phase lag: no stall; publishes nb
            SBAR;
            if (mh == 3) {
                SCHEDB;
                asm volatile("" ::: "memory");   // free: counters are 0 here
            }
        }
    }

    // Epilogue: direct stores. 16x16 C/D: col = lane&15, row = (lane>>4)*4+reg.
    const int row0 = bm * 256 + wm * 128 + kc * 4;
#pragma unroll
    for (int mf = 0; mf < 8; ++mf)
#pragma unroll
        for (int nf = 0; nf < 4; ++nf) {
            float* cp = C + (size_t)(row0 + mf * 16) * N + colb + nf * 16 + r15;
#pragma unroll
            for (int r = 0; r < 4; ++r)
                cp[(size_t)r * N] = acc[mf][nf][r] + bv[nf];
        }
}

extern "C" void kernel_launch(void* const* d_in, const int* in_sizes, int n_in,
                              void* d_out, int out_size, void* d_ws, size_t ws_size,
                              hipStream_t stream) {
    const float* x    = (const float*)d_in[0];   // [M, K]
    const float* w    = (const float*)d_in[1];   // [N, K]
    const float* bias = (const float*)d_in[2];   // [N]
    float* out = (float*)d_out;

    const int K = 2048;                 // IN
    const int N = in_sizes[2];          // OUT = 2048
    const int M = in_sizes[0] / K;      // 8192

    unsigned short* xb = (unsigned short*)d_ws;   // [M,K] bf16: 32 MB
    unsigned short* wb = xb + (size_t)M * K;      // [N,K] bf16 +-1: 8 MB

    const int nx8 = (M * K) / 8;
    const int nw4 = (N * K) / 4;
    const int nxB = (nx8 + 255) / 256;
    const int nwB = (nw4 + 255) / 256;
    prep_kernel<<<nxB + nwB, 256, 0, stream>>>(x, w, xb, wb, nx8, nxB, nw4);

    dim3 grid(N / 256, M / 256);        // (8, 32) = 256 blocks, 1/CU
    gemm_bin_kernel<<<grid, 512, 0, stream>>>(xb, wb, bias, out, M, N, K);
}